// Round 1
// baseline (310.157 us; speedup 1.0000x reference)
//
#include <hip/hip_runtime.h>
#include <hip/hip_bf16.h>

#define NTOK 16384        // 16*32*32 tokens
#define EDIM 256
#define NE   8192
#define NB   16
#define HW   1024
#define TOT  (NB*EDIM*HW) // 4194304

typedef __attribute__((ext_vector_type(8))) short bf16x8;
typedef __attribute__((ext_vector_type(4))) float f32x4;

// ---- workspace layout (bytes) ----
#define ACC_OFF   0
#define ENORM_OFF 256                         // 8192 f32
#define PVAL_OFF  33280                       // 16384*4 f32
#define PIDX_OFF  (PVAL_OFF + 262144)         // 16384*4 i32
#define IDXF_OFF  (PIDX_OFF + 262144)         // 16384 i32
#define ZF_OFF    (IDXF_OFF + 65536)          // 16384*256 bf16 (8 MB)
#define EMBB_OFF  (ZF_OFF + 8388608)          // 8192*256 bf16 (4 MB)

__device__ __forceinline__ ushort f2bf(float f) {
    __hip_bfloat16 h = __float2bfloat16(f);
    return *reinterpret_cast<ushort*>(&h);
}

// K1: cast emb -> bf16, compute ||e||^2 per row, zero the loss accumulator.
// grid 8192 x 64 (one wave per codebook row)
__global__ void k_emb(const float* __restrict__ emb, float* __restrict__ enorm,
                      ushort* __restrict__ embB, float* __restrict__ acc) {
    int row = blockIdx.x;
    int lane = threadIdx.x;
    if (row == 0 && lane == 0) *acc = 0.f;
    float4 v = *reinterpret_cast<const float4*>(emb + row * EDIM + lane * 4);
    float s = v.x * v.x + v.y * v.y + v.z * v.z + v.w * v.w;
#pragma unroll
    for (int off = 32; off; off >>= 1) s += __shfl_down(s, off);
    ushort4 u;
    u.x = f2bf(v.x); u.y = f2bf(v.y); u.z = f2bf(v.z); u.w = f2bf(v.w);
    *reinterpret_cast<ushort4*>(embB + row * EDIM + lane * 4) = u;
    if (lane == 0) enorm[row] = s;
}

// K2: transpose+cast z (B,C,H,W) f32 -> zf (B*HW, C) bf16 via LDS 64x64 tile.
// grid 1024 x 256
__global__ void k_tr(const float* __restrict__ z, ushort* __restrict__ zf) {
    __shared__ ushort lds[64][66];   // +2 pad: write-phase column reads spread banks
    int bid = blockIdx.x;
    int ct = bid & 3, hwt = (bid >> 2) & 15, b = bid >> 6;
    int c0 = ct * 64, hw0 = hwt * 64;
    int w = threadIdx.x >> 6, lane = threadIdx.x & 63;
#pragma unroll
    for (int i = 0; i < 16; i++) {
        int cl = w * 16 + i;
        lds[cl][lane] = f2bf(z[(b * EDIM + c0 + cl) * HW + hw0 + lane]);
    }
    __syncthreads();
#pragma unroll
    for (int i = 0; i < 16; i++) {
        int hl = w * 16 + i;
        zf[(b * HW + hw0 + hl) * EDIM + c0 + lane] = lds[lane][hl];
    }
}

// K3: bf16 MFMA distance + lane-local argmax.
// grid 512 x 256: bid = rowblock*4 + colsegment. Block = 128 rows; wave = 32 rows.
// Each wave holds its full A (32 rows x 256 K) in registers, loops 128 col-tiles
// of 16 codes, tracks per-lane best (score, tile) — no cross-lane ops in loop.
__global__ __launch_bounds__(256) void k_dist(const ushort* __restrict__ zf,
                                              const ushort* __restrict__ embB,
                                              const float* __restrict__ enorm,
                                              float* __restrict__ pval,
                                              int* __restrict__ pidx) {
    int bid = blockIdx.x;
    int rb = bid >> 2;
    int cs = bid & 3;
    int wid = threadIdx.x >> 6, lane = threadIdx.x & 63;
    int arow = lane & 15, kgrp = lane >> 4;
    int r0 = rb * 128 + wid * 32;

    bf16x8 a[2][8];
#pragma unroll
    for (int g = 0; g < 2; g++)
#pragma unroll
        for (int kc = 0; kc < 8; kc++)
            a[g][kc] = *reinterpret_cast<const bf16x8*>(
                zf + (r0 + g * 16 + arow) * EDIM + kc * 32 + kgrp * 8);

    float bv0[4], bv1[4];
    int bi0[4], bi1[4];
#pragma unroll
    for (int r = 0; r < 4; r++) {
        bv0[r] = -3.4e38f; bv1[r] = -3.4e38f; bi0[r] = 0; bi1[r] = 0;
    }

    for (int t = 0; t < 128; t++) {
        int tg = cs * 128 + t;          // global 16-wide column tile
        int col0 = tg * 16;
        const ushort* bp = embB + (col0 + arow) * EDIM + kgrp * 8;
        bf16x8 bfr[8];
#pragma unroll
        for (int kc = 0; kc < 8; kc++)
            bfr[kc] = *reinterpret_cast<const bf16x8*>(bp + kc * 32);
        f32x4 acc0 = {0.f, 0.f, 0.f, 0.f};
        f32x4 acc1 = {0.f, 0.f, 0.f, 0.f};
#pragma unroll
        for (int kc = 0; kc < 8; kc++) {
            acc0 = __builtin_amdgcn_mfma_f32_16x16x32_bf16(a[0][kc], bfr[kc], acc0, 0, 0, 0);
            acc1 = __builtin_amdgcn_mfma_f32_16x16x32_bf16(a[1][kc], bfr[kc], acc1, 0, 0, 0);
        }
        float en = enorm[col0 + arow];
#pragma unroll
        for (int r = 0; r < 4; r++) {
            float s0 = 2.f * acc0[r] - en;      // argmax(2 z.e - ||e||^2) == argmin dist
            if (s0 > bv0[r]) { bv0[r] = s0; bi0[r] = tg; }
            float s1 = 2.f * acc1[r] - en;
            if (s1 > bv1[r]) { bv1[r] = s1; bi1[r] = tg; }
        }
    }

    // cross-lane argmax within each 16-lane group; ties -> lower index
#pragma unroll
    for (int g = 0; g < 2; g++)
#pragma unroll
        for (int r = 0; r < 4; r++) {
            float v = g ? bv1[r] : bv0[r];
            int i = (g ? bi1[r] : bi0[r]) * 16 + arow;
#pragma unroll
            for (int off = 1; off < 16; off <<= 1) {
                float v2 = __shfl_xor(v, off);
                int i2 = __shfl_xor(i, off);
                if (v2 > v || (v2 == v && i2 < i)) { v = v2; i = i2; }
            }
            if (arow == 0) {
                int row = r0 + g * 16 + kgrp * 4 + r;
                pval[row * 4 + cs] = v;
                pidx[row * 4 + cs] = i;
            }
        }
}

// K4: combine the 4 column-segment partials per token. grid 64 x 256
__global__ void k_comb(const float* __restrict__ pval, const int* __restrict__ pidx,
                       int* __restrict__ idxf) {
    int n = blockIdx.x * blockDim.x + threadIdx.x;
    float4 v = *reinterpret_cast<const float4*>(pval + n * 4);
    int4 ii = *reinterpret_cast<const int4*>(pidx + n * 4);
    float bvv = v.x; int bii = ii.x;
    if (v.y > bvv) { bvv = v.y; bii = ii.y; }
    if (v.z > bvv) { bvv = v.z; bii = ii.z; }
    if (v.w > bvv) { bvv = v.w; bii = ii.w; }
    idxf[n] = bii;
}

// K5: gather z_q, straight-through output, fused loss partial sum. grid 4096 x 256
__global__ __launch_bounds__(256) void k_out(const float* __restrict__ z,
                                             const float* __restrict__ emb,
                                             const int* __restrict__ idxf,
                                             float* __restrict__ out,
                                             float* __restrict__ acc) {
    int t = blockIdx.x * blockDim.x + threadIdx.x;
    int gid = t * 4;
    int b = gid >> 18;
    int c = (gid >> 10) & 255;
    int hw0 = gid & 1023;
    int nbase = b * 1024 + hw0;
    float4 zv = *reinterpret_cast<const float4*>(z + gid);
    float zs[4] = {zv.x, zv.y, zv.z, zv.w};
    float o[4];
    float ls = 0.f;
#pragma unroll
    for (int q = 0; q < 4; q++) {
        int j = idxf[nbase + q];
        float e = emb[j * EDIM + c];
        float d = e - zs[q];
        o[q] = zs[q] + d;          // straight-through: zp + (zq - zp)
        ls += d * d;
    }
    *reinterpret_cast<float4*>(out + gid) = make_float4(o[0], o[1], o[2], o[3]);
#pragma unroll
    for (int off = 32; off; off >>= 1) ls += __shfl_down(ls, off);
    __shared__ float wsum[4];
    if ((threadIdx.x & 63) == 0) wsum[threadIdx.x >> 6] = ls;
    __syncthreads();
    if (threadIdx.x == 0) atomicAdd(acc, wsum[0] + wsum[1] + wsum[2] + wsum[3]);
}

// K6: finalize loss = 1.25 * sum / TOT
__global__ void k_fin(const float* __restrict__ acc, float* __restrict__ out) {
    out[TOT] = 1.25f * (*acc) / (float)TOT;
}

extern "C" void kernel_launch(void* const* d_in, const int* in_sizes, int n_in,
                              void* d_out, int out_size, void* d_ws, size_t ws_size,
                              hipStream_t stream) {
    const float* z = (const float*)d_in[0];
    const float* emb = (const float*)d_in[1];
    float* out = (float*)d_out;
    char* ws = (char*)d_ws;

    float* acc   = (float*)(ws + ACC_OFF);
    float* enorm = (float*)(ws + ENORM_OFF);
    float* pval  = (float*)(ws + PVAL_OFF);
    int*   pidx  = (int*)(ws + PIDX_OFF);
    int*   idxf  = (int*)(ws + IDXF_OFF);
    ushort* zf   = (ushort*)(ws + ZF_OFF);
    ushort* embB = (ushort*)(ws + EMBB_OFF);

    k_emb<<<NE, 64, 0, stream>>>(emb, enorm, embB, acc);
    k_tr<<<1024, 256, 0, stream>>>(z, zf);
    k_dist<<<512, 256, 0, stream>>>(zf, embB, enorm, pval, pidx);
    k_comb<<<64, 256, 0, stream>>>(pval, pidx, idxf);
    k_out<<<4096, 256, 0, stream>>>(z, emb, idxf, out, acc);
    k_fin<<<1, 1, 0, stream>>>(acc, out);
}

// Round 2
// 148.128 us; speedup vs baseline: 2.0938x; 2.0938x over previous
//
#include <hip/hip_runtime.h>
#include <hip/hip_bf16.h>

#define NTOK 16384        // 16*32*32 tokens
#define EDIM 256
#define NE   8192
#define NB   16
#define HW   1024
#define TOT  (NB*EDIM*HW) // 4194304
#define NSEG 8            // column segments
#define TPB  64           // 16-code tiles per segment = 8192/16/NSEG

typedef __attribute__((ext_vector_type(8))) short bf16x8;
typedef __attribute__((ext_vector_type(4))) float f32x4;

// ---- workspace layout (bytes) ----
#define ACC_OFF   0
#define ENORM_OFF 256                         // 8192 f32 = 32 KB
#define PVAL_OFF  33280                       // 16384*8 f32 = 512 KB
#define PIDX_OFF  (PVAL_OFF + 524288)         // 16384*8 i32 = 512 KB
#define IDXF_OFF  (PIDX_OFF + 524288)         // 16384 i32
#define ZF_OFF    (IDXF_OFF + 65536)          // 16384*256 bf16 (8 MB)
#define EMBB_OFF  (ZF_OFF + 8388608)          // 8192*256 bf16, TILED layout (4 MB)

__device__ __forceinline__ ushort f2bf(float f) {
    __hip_bfloat16 h = __float2bfloat16(f);
    return *reinterpret_cast<ushort*>(&h);
}

// async global->LDS, 16B per lane; l must be wave-uniform
__device__ __forceinline__ void gl16(const void* g, void* l) {
    __builtin_amdgcn_global_load_lds(
        (const __attribute__((address_space(1))) void*)g,
        (__attribute__((address_space(3))) void*)l, 16, 0, 0);
}

// K1: cast emb -> bf16 in MFMA-fragment-tile order, ||e||^2 per row, zero acc.
// Tiled layout (ushort units): tile*4096 + kc*512 + (kgrp*16 + arow)*8 + e
//   where code = tile*16+arow, k = kc*32 + kgrp*8 + e. This makes the LDS
//   stage a linear copy and the ds_read_b128 fragment fetch conflict-free.
// grid 8192 x 64
__global__ void k_emb(const float* __restrict__ emb, float* __restrict__ enorm,
                      ushort* __restrict__ embB, float* __restrict__ acc) {
    int row = blockIdx.x;
    int l = threadIdx.x;
    if (row == 0 && l == 0) *acc = 0.f;
    float4 v = *reinterpret_cast<const float4*>(emb + row * EDIM + l * 4);
    float s = v.x * v.x + v.y * v.y + v.z * v.z + v.w * v.w;
#pragma unroll
    for (int off = 32; off; off >>= 1) s += __shfl_down(s, off);
    ushort4 u;
    u.x = f2bf(v.x); u.y = f2bf(v.y); u.z = f2bf(v.z); u.w = f2bf(v.w);
    int tile = row >> 4, arow = row & 15;
    int kc = l >> 3, kgrp = (l >> 1) & 3, e0 = (l & 1) * 4;
    *reinterpret_cast<ushort4*>(embB + tile * 4096 + kc * 512 +
                                (kgrp * 16 + arow) * 8 + e0) = u;
    if (l == 0) enorm[row] = s;
}

// K2: transpose+cast z (B,C,H,W) f32 -> zf (B*HW, C) bf16. grid 1024 x 256
__global__ void k_tr(const float* __restrict__ z, ushort* __restrict__ zf) {
    __shared__ ushort lds[64][66];
    int bid = blockIdx.x;
    int ct = bid & 3, hwt = (bid >> 2) & 15, b = bid >> 6;
    int c0 = ct * 64, hw0 = hwt * 64;
    int w = threadIdx.x >> 6, lane = threadIdx.x & 63;
#pragma unroll
    for (int i = 0; i < 16; i++) {
        int cl = w * 16 + i;
        lds[cl][lane] = f2bf(z[(b * EDIM + c0 + cl) * HW + hw0 + lane]);
    }
    __syncthreads();
#pragma unroll
    for (int i = 0; i < 16; i++) {
        int hl = w * 16 + i;
        zf[(b * HW + hw0 + hl) * EDIM + c0 + lane] = lds[lane][hl];
    }
}

// K3: bf16 MFMA distance + lane-local argmax.
// grid 1024 = 128 rowblocks x 8 col segments; block = 4 waves x 32 rows.
// A (32x256 per wave) in registers; B tiles double-buffered in LDS via
// global_load_lds; counted vmcnt(2) keeps prefetch in flight across raw
// barriers. enorm staged to LDS up front so no vmem consumption in loop.
__global__ __launch_bounds__(256, 4) void k_dist(const ushort* __restrict__ zf,
                                                 const ushort* __restrict__ embB,
                                                 const float* __restrict__ enorm,
                                                 float* __restrict__ pval,
                                                 int* __restrict__ pidx) {
    __shared__ __align__(16) ushort lbuf[2][4096];   // 2 x 8 KB B tiles
    __shared__ float en_lds[TPB * 16];               // 4 KB segment enorm
    int bid = blockIdx.x;
    int rb = bid >> 3;
    int cs = bid & 7;
    int tid = threadIdx.x;
    int wid = tid >> 6, lane = tid & 63;
    int arow = lane & 15, kgrp = lane >> 4;
    int r0 = rb * 128 + wid * 32;

    // enorm segment -> LDS (one-time)
    {
        float4 ev = *reinterpret_cast<const float4*>(enorm + cs * (TPB * 16) + tid * 4);
        *reinterpret_cast<float4*>(en_lds + tid * 4) = ev;
    }

    // A fragments: 32 rows x 256 K per wave, 64 VGPRs
    bf16x8 a[2][8];
#pragma unroll
    for (int g = 0; g < 2; g++)
#pragma unroll
        for (int kc = 0; kc < 8; kc++)
            a[g][kc] = *reinterpret_cast<const bf16x8*>(
                zf + (r0 + g * 16 + arow) * EDIM + kc * 32 + kgrp * 8);

    __syncthreads();   // en_lds visible; drains the one-time loads

    const ushort* tbase = embB + (size_t)(cs * TPB) * 4096;

    float bv0[4], bv1[4];
    int bi0[4], bi1[4];
#pragma unroll
    for (int r = 0; r < 4; r++) {
        bv0[r] = -3.4e38f; bv1[r] = -3.4e38f; bi0[r] = 0; bi1[r] = 0;
    }

    // prologue: stage tile 0
    gl16(tbase + (size_t)wid * 512 + lane * 8, &lbuf[0][wid * 512]);
    gl16(tbase + 2048 + (size_t)wid * 512 + lane * 8, &lbuf[0][2048 + wid * 512]);

    int cur = 0;
    for (int t = 0; t < TPB; ++t) {
        if (t + 1 < TPB) {
            const ushort* g = tbase + (size_t)(t + 1) * 4096 + wid * 512 + lane * 8;
            gl16(g, &lbuf[cur ^ 1][wid * 512]);
            gl16(g + 2048, &lbuf[cur ^ 1][2048 + wid * 512]);
            asm volatile("s_waitcnt vmcnt(2)" ::: "memory");  // tile t landed; t+1 in flight
        } else {
            asm volatile("s_waitcnt vmcnt(0)" ::: "memory");
        }
        __builtin_amdgcn_s_barrier();
        asm volatile("" ::: "memory");

        const ushort* lp = &lbuf[cur][0];
        f32x4 acc0 = {0.f, 0.f, 0.f, 0.f};
        f32x4 acc1 = {0.f, 0.f, 0.f, 0.f};
#pragma unroll
        for (int h = 0; h < 2; ++h) {
            bf16x8 bfr[4];
#pragma unroll
            for (int q = 0; q < 4; q++)
                bfr[q] = *reinterpret_cast<const bf16x8*>(lp + (h * 4 + q) * 512 + lane * 8);
#pragma unroll
            for (int q = 0; q < 4; q++) {
                acc0 = __builtin_amdgcn_mfma_f32_16x16x32_bf16(a[0][h * 4 + q], bfr[q], acc0, 0, 0, 0);
                acc1 = __builtin_amdgcn_mfma_f32_16x16x32_bf16(a[1][h * 4 + q], bfr[q], acc1, 0, 0, 0);
            }
        }

        int tg = cs * TPB + t;
        float en = en_lds[t * 16 + arow];
#pragma unroll
        for (int r = 0; r < 4; r++) {
            float s0 = 2.f * acc0[r] - en;      // argmax(2 z.e - ||e||^2) == argmin dist
            if (s0 > bv0[r]) { bv0[r] = s0; bi0[r] = tg; }
            float s1 = 2.f * acc1[r] - en;
            if (s1 > bv1[r]) { bv1[r] = s1; bi1[r] = tg; }
        }

        asm volatile("" ::: "memory");
        __builtin_amdgcn_s_barrier();   // all waves done reading lbuf[cur]
        cur ^= 1;
    }

    // cross-lane argmax within each 16-lane group; ties -> lower index
#pragma unroll
    for (int g = 0; g < 2; g++)
#pragma unroll
        for (int r = 0; r < 4; r++) {
            float v = g ? bv1[r] : bv0[r];
            int i = (g ? bi1[r] : bi0[r]) * 16 + arow;
#pragma unroll
            for (int off = 1; off < 16; off <<= 1) {
                float v2 = __shfl_xor(v, off);
                int i2 = __shfl_xor(i, off);
                if (v2 > v || (v2 == v && i2 < i)) { v = v2; i = i2; }
            }
            if (arow == 0) {
                int row = r0 + g * 16 + kgrp * 4 + r;
                pval[row * NSEG + cs] = v;
                pidx[row * NSEG + cs] = i;
            }
        }
}

// K4: combine the 8 column-segment partials per token. grid 64 x 256
__global__ void k_comb(const float* __restrict__ pval, const int* __restrict__ pidx,
                       int* __restrict__ idxf) {
    int n = blockIdx.x * blockDim.x + threadIdx.x;
    float4 v0 = *reinterpret_cast<const float4*>(pval + n * 8);
    float4 v1 = *reinterpret_cast<const float4*>(pval + n * 8 + 4);
    int4 i0 = *reinterpret_cast<const int4*>(pidx + n * 8);
    int4 i1 = *reinterpret_cast<const int4*>(pidx + n * 8 + 4);
    float bvv = v0.x; int bii = i0.x;
    if (v0.y > bvv) { bvv = v0.y; bii = i0.y; }
    if (v0.z > bvv) { bvv = v0.z; bii = i0.z; }
    if (v0.w > bvv) { bvv = v0.w; bii = i0.w; }
    if (v1.x > bvv) { bvv = v1.x; bii = i1.x; }
    if (v1.y > bvv) { bvv = v1.y; bii = i1.y; }
    if (v1.z > bvv) { bvv = v1.z; bii = i1.z; }
    if (v1.w > bvv) { bvv = v1.w; bii = i1.w; }
    idxf[n] = bii;
}

// K5: gather z_q, straight-through output, fused loss partial sum. grid 4096 x 256
__global__ __launch_bounds__(256) void k_out(const float* __restrict__ z,
                                             const float* __restrict__ emb,
                                             const int* __restrict__ idxf,
                                             float* __restrict__ out,
                                             float* __restrict__ acc) {
    int t = blockIdx.x * blockDim.x + threadIdx.x;
    int gid = t * 4;
    int b = gid >> 18;
    int c = (gid >> 10) & 255;
    int hw0 = gid & 1023;
    int nbase = b * 1024 + hw0;
    float4 zv = *reinterpret_cast<const float4*>(z + gid);
    float zs[4] = {zv.x, zv.y, zv.z, zv.w};
    float o[4];
    float ls = 0.f;
#pragma unroll
    for (int q = 0; q < 4; q++) {
        int j = idxf[nbase + q];
        float e = emb[j * EDIM + c];
        float d = e - zs[q];
        o[q] = zs[q] + d;          // straight-through: zp + (zq - zp)
        ls += d * d;
    }
    *reinterpret_cast<float4*>(out + gid) = make_float4(o[0], o[1], o[2], o[3]);
#pragma unroll
    for (int off = 32; off; off >>= 1) ls += __shfl_down(ls, off);
    __shared__ float wsum[4];
    if ((threadIdx.x & 63) == 0) wsum[threadIdx.x >> 6] = ls;
    __syncthreads();
    if (threadIdx.x == 0) atomicAdd(acc, wsum[0] + wsum[1] + wsum[2] + wsum[3]);
}

// K6: finalize loss = 1.25 * sum / TOT
__global__ void k_fin(const float* __restrict__ acc, float* __restrict__ out) {
    out[TOT] = 1.25f * (*acc) / (float)TOT;
}

extern "C" void kernel_launch(void* const* d_in, const int* in_sizes, int n_in,
                              void* d_out, int out_size, void* d_ws, size_t ws_size,
                              hipStream_t stream) {
    const float* z = (const float*)d_in[0];
    const float* emb = (const float*)d_in[1];
    float* out = (float*)d_out;
    char* ws = (char*)d_ws;

    float* acc   = (float*)(ws + ACC_OFF);
    float* enorm = (float*)(ws + ENORM_OFF);
    float* pval  = (float*)(ws + PVAL_OFF);
    int*   pidx  = (int*)(ws + PIDX_OFF);
    int*   idxf  = (int*)(ws + IDXF_OFF);
    ushort* zf   = (ushort*)(ws + ZF_OFF);
    ushort* embB = (ushort*)(ws + EMBB_OFF);

    k_emb<<<NE, 64, 0, stream>>>(emb, enorm, embB, acc);
    k_tr<<<1024, 256, 0, stream>>>(z, zf);
    k_dist<<<1024, 256, 0, stream>>>(zf, embB, enorm, pval, pidx);
    k_comb<<<64, 256, 0, stream>>>(pval, pidx, idxf);
    k_out<<<4096, 256, 0, stream>>>(z, emb, idxf, out, acc);
    k_fin<<<1, 1, 0, stream>>>(acc, out);
}